// Round 11
// baseline (222.281 us; speedup 1.0000x reference)
//
#include <hip/hip_runtime.h>
#include <math.h>

#define T_DIM 2048
#define B_DIM 96
#define C_DIM 128
#define L_DIM 128
#define LOG2E 1.4426950408889634f
#define LN2 0.69314718055994531f
#define SMOOTH 0.1f
#define SENT (-(1 << 30))       // virgin lane frame (f32-exact power of 2)
#define NPH 64                  // 64 phases x 32 steps cover t = 1..2047

// wave shift-right-by-1, 0-fill — the proven helper (float only).
__device__ __forceinline__ float dpp_shr1_f(float x) {
  return __int_as_float(__builtin_amdgcn_update_dpp(
      0, __float_as_int(x), 0x138 /*WAVE_SR1*/, 0xF, 0xF, true));
}

// R9/R10-proven CTC step math (unchanged). Consumes pAv/pBv/pKv.
#define CTC_MATH(k_) do {                                                    \
  const float r3s = dpp_shr1_f(r3);                                          \
  const int   Es  = (int)dpp_shr1_f((float)E);                               \
  const int   be  = (__float_as_int(r3s) >> 23) & 0xFF;                      \
  int diff = (be - 187) + (Es - E);                                          \
  diff = (__float_as_int(r3s) != 0 && diff > 0) ? diff : 0;                  \
  r0 = ldexpf(r0, -diff); r1 = ldexpf(r1, -diff); r2 = ldexpf(r2, -diff);    \
  r3 = ldexpf(r3, -diff); r4 = ldexpf(r4, -diff);                            \
  E += diff;                                                                 \
  const float d3 = ldexpf(r3s, Es - E);                                      \
  const float n0 = (r0 + d3) * pKv;                                          \
  const float n1 = __builtin_fmaf(skA, d3, r0 + r1) * pAv;                   \
  const float n2 = (r2 + r1) * pKv;                                          \
  const float n3 = __builtin_fmaf(skB, r1, r3 + r2) * pBv;                   \
  const float n4 = (r4 + r3) * pKv;                                          \
  r0 = n0; r1 = n1; r2 = n2; r3 = n3; r4 = n4;                               \
  if (((k_) & 3) == 3) {                                                     \
    const float m = fmaxf(fmaxf(fmaxf(r0, r1), fmaxf(r2, r3)), r4);          \
    const int sh2 = (m > 0.0f)                                               \
                      ? (187 - ((__float_as_int(m) >> 23) & 0xFF)) : 0;      \
    r0 = ldexpf(r0, sh2); r1 = ldexpf(r1, sh2); r2 = ldexpf(r2, sh2);        \
    r3 = ldexpf(r3, sh2); r4 = ldexpf(r4, sh2);                              \
    E -= sh2;                                                                \
  }                                                                          \
} while (0)

#define CTC_STEP_PF(k_) do {                                                 \
  const float pAv = fA[(k_) & 3], pBv = fB[(k_) & 3], pKv = fK[(k_) & 3];    \
  const float* nr = cur + ((k_) + 4) * C_DIM;                                \
  fA[(k_) & 3] = nr[tgA]; fB[(k_) & 3] = nr[tgB]; fK[(k_) & 3] = nr[0];      \
  CTC_MATH(k_);                                                              \
} while (0)

#define CTC_STEP_NOPF(k_) do {                                               \
  const float pAv = fA[(k_) & 3], pBv = fB[(k_) & 3], pKv = fK[(k_) & 3];    \
  CTC_MATH(k_);                                                              \
} while (0)

// One block (512 thr, 8 waves) per TWO samples.
//   half h = tid>>8 handles sample b = 2*blockIdx.x + h.
//   Within a half: tid_h<64 -> consumer wave (CTC); tid_h in [64,256) ->
//   3 producer waves (stream rows, pre-exponentiate into LDS, KL sum).
//   Consumers are block-waves 0 and 4 -> BOTH on SIMD 0: their two
//   independent dependency chains interleave, hiding VALU latency.
//   LDS: per-half 2-deep ring (exactly 64 KB total). Consumer prefetch
//   stops 4 steps early so it never reads the buffer being filled.
__global__ __launch_bounds__(512) void ctc_fused_kernel(
    const float* __restrict__ lp, const int* __restrict__ targets,
    const int* __restrict__ in_len, const int* __restrict__ tg_len,
    float* __restrict__ ws)
{
  const int tid   = threadIdx.x;
  const int half  = tid >> 8;                      // 0 or 1
  const int tid_h = tid & 255;
  const int b     = blockIdx.x * 2 + half;
  const size_t RSTR = (size_t)B_DIM * C_DIM;       // floats per t-row
  const int Tb = in_len[b];
  const float* base = lp + (size_t)b * C_DIM;

  __shared__ float rows[2][2][32][C_DIM];          // 64 KB: [half][buf][row][c]

  // consumer state
  int tgA = 0, tgB = 0;
  float skA = 0.f, skB = 0.f;
  float r0 = 0.f, r1 = 0.f, r2 = 0.f, r3 = 0.f, r4 = 0.f;
  int E = SENT;
  float fA[4], fB[4], fK[4];
  float klacc = 0.f;                               // producers only

  if (tid_h < 64) {
    const int l = tid_h;
    tgA = targets[b * L_DIM + 2 * l];
    tgB = targets[b * L_DIM + 2 * l + 1];
    skA = (l > 0 && tgA != targets[b * L_DIM + 2 * l - 1]) ? 1.f : 0.f;
    skB = (tgB != tgA) ? 1.f : 0.f;
    if (l == 0) {
      r0 = __builtin_amdgcn_exp2f(base[0]   * LOG2E);
      r1 = __builtin_amdgcn_exp2f(base[tgA] * LOG2E);
      E = 0;
    }
  } else {
    // prefill buf0 with rows t=1..32 (as probs); KL for t=0..32
    const int ptid = tid_h - 64;                   // 0..191
    #pragma unroll
    for (int i = 0; i < 6; ++i) {
      const int task = i * 192 + ptid;             // 32 rows x 32 float4
      if (task < 1024) {
        const int row = task >> 5;
        const int c4  = task & 31;
        const int t   = 1 + row;
        const float4 v = *(const float4*)(base + (size_t)t * RSTR + c4 * 4);
        float4 w;
        w.x = __builtin_amdgcn_exp2f(v.x * LOG2E);
        w.y = __builtin_amdgcn_exp2f(v.y * LOG2E);
        w.z = __builtin_amdgcn_exp2f(v.z * LOG2E);
        w.w = __builtin_amdgcn_exp2f(v.w * LOG2E);
        *(float4*)&rows[half][0][row][c4 * 4] = w;
        if (t < Tb) {
          float s = v.x + v.y + v.z + v.w;
          if (c4 == 0) s -= v.x;
          klacc += s;
        }
      }
    }
    if (ptid < 32 && 0 < Tb) {                     // row t=0 KL contribution
      const float4 v = *(const float4*)(base + ptid * 4);
      float s = v.x + v.y + v.z + v.w;
      if (ptid == 0) s -= v.x;
      klacc += s;
    }
  }
  __syncthreads();

  for (int p = 0; p < NPH; ++p) {
    const float* cur = &rows[half][p & 1][0][0];
    float*       nxt = &rows[half][(p + 1) & 1][0][0];
    if (tid_h < 64) {
      // prologue: (re)load pipeline slots with rows 0..3 of cur
      #pragma unroll
      for (int j = 0; j < 4; ++j) {
        fA[j] = cur[j * C_DIM + tgA];
        fB[j] = cur[j * C_DIM + tgB];
        fK[j] = cur[j * C_DIM];
      }
      if (32 * p + 33 <= Tb) {
        // FAST phase: all 32 steps active, branch-free
        #pragma unroll
        for (int k = 0; k < 28; ++k) { CTC_STEP_PF(k); }
        #pragma unroll
        for (int k = 28; k < 32; ++k) { CTC_STEP_NOPF(k); }
      } else {
        // tail / short-length phase: per-step guard
        #pragma unroll
        for (int k = 0; k < 32; ++k) {
          const int t = 1 + 32 * p + k;
          if (t < Tb) {
            if (k < 28) { CTC_STEP_PF(k); } else { CTC_STEP_NOPF(k); }
          }
        }
      }
    } else {
      // producers: fill nxt with rows t = 33+32p .. 64+32p (as probs)
      const int ptid = tid_h - 64;
      const int t0 = 33 + 32 * p;
      if (t0 < T_DIM) {
        #pragma unroll
        for (int i = 0; i < 6; ++i) {
          const int task = i * 192 + ptid;         // 32 rows x 32 float4
          if (task < 1024) {
            const int row = task >> 5;
            const int c4  = task & 31;
            const int t   = t0 + row;
            if (t < T_DIM) {
              const float4 v = *(const float4*)(base + (size_t)t * RSTR + c4 * 4);
              float4 w;
              w.x = __builtin_amdgcn_exp2f(v.x * LOG2E);
              w.y = __builtin_amdgcn_exp2f(v.y * LOG2E);
              w.z = __builtin_amdgcn_exp2f(v.z * LOG2E);
              w.w = __builtin_amdgcn_exp2f(v.w * LOG2E);
              *(float4*)&nxt[row * C_DIM + c4 * 4] = w;
              if (t < Tb) {
                float s = v.x + v.y + v.z + v.w;
                if (c4 == 0) s -= v.x;
                klacc += s;
              }
            }
          }
        }
      }
    }
    __syncthreads();
  }

  // ---------------- epilogue: reuse ring memory for als/klred ----------------
  float* reg = &rows[half][0][0][0];               // 16384 floats per half
  float* als = reg;                                // 257 floats
  float* klr = reg + 272;                          // 3 floats
  if (tid_h < 64) {
    const int l = tid_h;
    const float Ef = (float)E;                     // |E| <~ 5e4: exact
    als[4 * l + 0] = __builtin_amdgcn_logf(r0) + Ef;
    als[4 * l + 1] = __builtin_amdgcn_logf(r1) + Ef;
    als[4 * l + 2] = __builtin_amdgcn_logf(r2) + Ef;
    als[4 * l + 3] = __builtin_amdgcn_logf(r3) + Ef;
    if (l == 63) als[256] = __builtin_amdgcn_logf(r4) + Ef;
  } else {
    float tot = klacc;
    tot += __shfl_xor(tot, 1, 64);
    tot += __shfl_xor(tot, 2, 64);
    tot += __shfl_xor(tot, 4, 64);
    tot += __shfl_xor(tot, 8, 64);
    tot += __shfl_xor(tot, 16, 64);
    tot += __shfl_xor(tot, 32, 64);
    if ((tid_h & 63) == 0) klr[(tid_h >> 6) - 1] = tot;
  }
  __syncthreads();
  if (tid_h == 0) {
    const int Lt = tg_len[b];
    const float xa = als[2 * Lt], xb = als[2 * Lt - 1];  // log2 domain
    const float mm = fmaxf(xa, xb);
    float loss = 0.f;
    if (mm > -1e30f) {
      loss = -((mm + __builtin_amdgcn_logf(
          __builtin_amdgcn_exp2f(xa - mm) + __builtin_amdgcn_exp2f(xb - mm))) * LN2);
    }
    ws[b] = loss;                                  // zero_infinity: loss 0
    ws[B_DIM + b] = klr[0] + klr[1] + klr[2];
  }
}

__global__ __launch_bounds__(128) void ctc_finalize_kernel(
    const float* __restrict__ ws, const int* __restrict__ in_len,
    float* __restrict__ out)
{
  __shared__ float red[128];
  const int tid = threadIdx.x;
  float v = 0.0f;
  if (tid < B_DIM) {
    const float ctc  = ws[tid];
    const float kls  = ws[B_DIM + tid];
    const float u    = 1.0f / (C_DIM - 1);
    const float logu = -4.8441870864585910f;       // log(1/127)
    const float klmean = logu - u * kls / (float)in_len[tid];
    v = (1.0f - SMOOTH) * ctc + SMOOTH * klmean;
  }
  red[tid] = v;
  __syncthreads();
  for (int off = 64; off > 0; off >>= 1) {
    if (tid < off) red[tid] += red[tid + off];
    __syncthreads();
  }
  if (tid == 0) out[0] = red[0] / (float)B_DIM;
}

extern "C" void kernel_launch(void* const* d_in, const int* in_sizes, int n_in,
                              void* d_out, int out_size, void* d_ws, size_t ws_size,
                              hipStream_t stream) {
  const float* lp      = (const float*)d_in[0];
  const int* targets   = (const int*)d_in[1];
  const int* in_len    = (const int*)d_in[2];
  const int* tg_len    = (const int*)d_in[3];
  float* ws  = (float*)d_ws;
  float* out = (float*)d_out;

  hipLaunchKernelGGL(ctc_fused_kernel, dim3(B_DIM / 2), dim3(512), 0, stream,
                     lp, targets, in_len, tg_len, ws);
  hipLaunchKernelGGL(ctc_finalize_kernel, dim3(1), dim3(128), 0, stream,
                     ws, in_len, out);
}